// Round 2
// baseline (547.759 us; speedup 1.0000x reference)
//
#include <hip/hip_runtime.h>
#include <cstdint>
#include <cstddef>

// Problem dims (fixed by reference)
#define BATCH   4096
#define IN_DIM  2048
#define OUT_DIM 2048
#define KDIM    4096   // IN_DIM + OUT_DIM
#define NT      128    // number of 32-wide K tiles

typedef __bf16 bf16x8 __attribute__((ext_vector_type(8)));
typedef float  floatx4 __attribute__((ext_vector_type(4)));

__device__ __forceinline__ unsigned short f2bf(float f) {
  unsigned int u = __float_as_uint(f);
  u += 0x7FFFu + ((u >> 16) & 1u);   // round-to-nearest-even
  return (unsigned short)(u >> 16);
}

__device__ __forceinline__ void async16(const void* g, void* l) {
  __builtin_amdgcn_global_load_lds(
      (const __attribute__((address_space(1))) unsigned int*)g,
      (__attribute__((address_space(3))) unsigned int*)l, 16, 0, 0);
}

// fast tanh via exp2-backed __expf; exact at saturation (exp overflow -> +-1)
__device__ __forceinline__ float tanh_fast(float x) {
  return 1.f - 2.f / (__expf(2.f * x) + 1.f);
}

// ---------------------------------------------------------------------------
// Pack A = [X | H] row-major 4096 x 4096 bf16   (unchanged, verified)
// ---------------------------------------------------------------------------
__global__ __launch_bounds__(256) void pack_A_kernel(
    const float* __restrict__ X, const float* __restrict__ H,
    unsigned short* __restrict__ A) {
  int idx = blockIdx.x * 256 + threadIdx.x;   // 0 .. 4194303
  int e = idx << 2;                           // element index (groups of 4)
  int m = e >> 12;                            // /4096
  int k = e & 4095;
  const float* src = (k < IN_DIM) ? (X + (size_t)m * IN_DIM + k)
                                  : (H + (size_t)m * OUT_DIM + (k - IN_DIM));
  float4 v = *(const float4*)src;
  ushort4 o;
  o.x = f2bf(v.x); o.y = f2bf(v.y); o.z = f2bf(v.z); o.w = f2bf(v.w);
  *(ushort4*)(A + e) = o;
}

// ---------------------------------------------------------------------------
// Pack Bt: 8192(n) x 4096(k) bf16, n = gate*2048 + c, gates ordered f,i,o,g.
// (unchanged, verified)
// ---------------------------------------------------------------------------
__global__ __launch_bounds__(256) void pack_B_kernel(
    const float* __restrict__ Wxf, const float* __restrict__ Wxi,
    const float* __restrict__ Wxo, const float* __restrict__ Wxg,
    const float* __restrict__ Whf, const float* __restrict__ Whi,
    const float* __restrict__ Who, const float* __restrict__ Whg,
    unsigned short* __restrict__ Bt) {
  __shared__ float tile[64][33];
  int bx = blockIdx.x;             // 0 .. 16383
  int kT = bx & 63;                // 0..63
  int nT = bx >> 6;                // 0..255
  int k0 = kT * 64, n0 = nT * 32;
  int g = n0 >> 11;                // gate; tiles never straddle (2048%32==0)
  int c0 = n0 & 2047;
  const float* W;
  int kk0;
  if (k0 < IN_DIM) {               // 2048 % 64 == 0: no straddle in k either
    kk0 = k0;
    W = (g == 0) ? Wxf : (g == 1) ? Wxi : (g == 2) ? Wxo : Wxg;
  } else {
    kk0 = k0 - IN_DIM;
    W = (g == 0) ? Whf : (g == 1) ? Whi : (g == 2) ? Who : Whg;
  }
  int t = threadIdx.x;
#pragma unroll
  for (int i = 0; i < 2; ++i) {
    int idx = i * 256 + t;
    int lk = idx >> 3, lc = (idx & 7) * 4;
    float4 v = *(const float4*)(W + (size_t)(kk0 + lk) * 2048 + c0 + lc);
    tile[lk][lc]     = v.x;
    tile[lk][lc + 1] = v.y;
    tile[lk][lc + 2] = v.z;
    tile[lk][lc + 3] = v.w;
  }
  __syncthreads();
  int ln = t >> 3, k8 = (t & 7) * 8;
  unsigned int p[4];
#pragma unroll
  for (int j = 0; j < 4; ++j) {
    unsigned int lo = f2bf(tile[k8 + 2 * j][ln]);
    unsigned int hi = f2bf(tile[k8 + 2 * j + 1][ln]);
    p[j] = lo | (hi << 16);
  }
  uint4 o = make_uint4(p[0], p[1], p[2], p[3]);
  *(uint4*)(Bt + (size_t)(n0 + ln) * KDIM + k0 + k8) = o;
}

// ---------------------------------------------------------------------------
// Fused LSTM GEMM — minimum 2-phase pipelined schedule (T3-lite + T5).
//   Same tile/indexing as the verified kernel: block = 256 thr (4 waves),
//   tile 256(M) x 32 cols x 4 gates, 12 ds_read_b128 -> 32 MFMA per K-step.
//   NEW: double-buffered LDS (2 x 24 KB). Tile t+1's 6 global_load_lds are
//   issued BEFORE tile t's compute; the single __syncthreads() per K-step
//   (vmcnt(0)+lgkmcnt(0)+barrier) lands the prefetch AFTER ~32 MFMAs have
//   covered the load latency, instead of draining before any compute.
//   Ledger: stage(t+1) writes buf (t+1)&1; its last readers (iteration t-1)
//   all completed their ds_reads (lgkmcnt(0)) before passing the end-of-(t-1)
//   barrier, which every wave crossed before any wave issues stage(t+1).
//   LDS chunk swizzle unchanged: c' = c ^ ((row>>1)&3), measured 0 conflicts.
// ---------------------------------------------------------------------------
__global__ __launch_bounds__(256, 2) void lstm_gemm_fused(
    const unsigned short* __restrict__ A,    // 4096 x 4096 bf16
    const unsigned short* __restrict__ Bt,   // 8192 x 4096 bf16
    const float* __restrict__ Cin,           // 4096 x 2048
    const float* __restrict__ bF, const float* __restrict__ bI,
    const float* __restrict__ bO, const float* __restrict__ bG,
    float* __restrict__ outC, float* __restrict__ outY) {
  __shared__ unsigned short lA[2][256 * 32];   // 2 x 16 KB
  __shared__ unsigned short lB[2][128 * 32];   // 2 x 8 KB; rows = 4g x 32n

  const int t = threadIdx.x;
  const int lane = t & 63;
  const int w = t >> 6;                      // wave id: m-quarter
  const int mBase = blockIdx.y * 256;
  const int nBase = blockIdx.x * 32;         // within one gate's 2048 cols

  floatx4 acc[4][2][4];                      // [gate][nfrag][mtile]
#pragma unroll
  for (int g = 0; g < 4; ++g)
#pragma unroll
    for (int nf = 0; nf < 2; ++nf)
#pragma unroll
      for (int mt = 0; mt < 4; ++mt) acc[g][nf][mt] = (floatx4){0.f, 0.f, 0.f, 0.f};

  // ---- staging addresses. thread t stages LDS row (t>>2), chunk c'=(t&3);
  // swizzle: global chunk c = c' ^ ((row>>1)&3) = (t&3) ^ ((t>>3)&3).
  const int rowT = t >> 2;                   // 0..63
  const int cswz = (((t & 3) ^ ((t >> 3) & 3))) * 16;   // byte offset in row
  const char* aG = (const char*)(A + (size_t)(mBase + rowT) * KDIM) + cswz;
  const size_t aStep = (size_t)64 * KDIM * 2;           // 64 rows, bytes
  const int r1 = 64 + rowT;
  const char* bG0 = (const char*)(Bt + (size_t)((rowT >> 5) * 2048 + nBase + (rowT & 31)) * KDIM) + cswz;
  const char* bG1 = (const char*)(Bt + (size_t)((r1 >> 5) * 2048 + nBase + (r1 & 31)) * KDIM) + cswz;
  char* lAd = (char*)lA + t * 16;            // + buf*16384
  char* lBd = (char*)lB + t * 16;            // + buf*8192

  const int fr = lane & 15;                  // fragment row (m or n)
  const int fk = lane >> 4;                  // which 8-wide k chunk
  const int fkx = fk ^ ((fr >> 1) & 3);      // swizzled chunk (lane-constant)

  // ---- prologue: stage tile 0 into buf 0, land it
  {
    async16(aG,             lAd);
    async16(aG + aStep,     lAd + 4096);
    async16(aG + 2 * aStep, lAd + 8192);
    async16(aG + 3 * aStep, lAd + 12288);
    async16(bG0,            lBd);
    async16(bG1,            lBd + 4096);
  }
  __syncthreads();                           // vmcnt(0): tile 0 resident

  for (int kt = 0; kt < NT; ++kt) {
    const int cur = kt & 1, nxt = cur ^ 1;
    // ---- issue next tile's staging FIRST (latency hides under compute)
    if (kt + 1 < NT) {
      const int kb = (kt + 1) * 64;          // bytes: 32 k * 2
      async16(aG + kb,             lAd + nxt * 16384);
      async16(aG + kb + aStep,     lAd + nxt * 16384 + 4096);
      async16(aG + kb + 2 * aStep, lAd + nxt * 16384 + 8192);
      async16(aG + kb + 3 * aStep, lAd + nxt * 16384 + 12288);
      async16(bG0 + kb,            lBd + nxt * 8192);
      async16(bG1 + kb,            lBd + nxt * 8192 + 4096);
    }
    // ---- compute current tile
    const bf16x8* A8 = (const bf16x8*)lA[cur];
    const bf16x8* B8 = (const bf16x8*)lB[cur];
    bf16x8 af[4], bfrag[8];
#pragma unroll
    for (int mt = 0; mt < 4; ++mt)
      af[mt] = A8[(w * 64 + mt * 16 + fr) * 4 + fkx];
#pragma unroll
    for (int g = 0; g < 4; ++g)
#pragma unroll
      for (int nf = 0; nf < 2; ++nf)
        bfrag[g * 2 + nf] = B8[(g * 32 + nf * 16 + fr) * 4 + fkx];
    __builtin_amdgcn_s_setprio(1);
#pragma unroll
    for (int g = 0; g < 4; ++g)
#pragma unroll
      for (int nf = 0; nf < 2; ++nf)
#pragma unroll
        for (int mt = 0; mt < 4; ++mt)
          acc[g][nf][mt] = __builtin_amdgcn_mfma_f32_16x16x32_bf16(
              af[mt], bfrag[g * 2 + nf], acc[g][nf][mt], 0, 0, 0);
    __builtin_amdgcn_s_setprio(0);
    // ---- single barrier per K-step: lands prefetch (vmcnt 0), publishes
    // that all waves finished reading buf[cur] (lgkmcnt 0 + barrier).
    __syncthreads();
  }

  // ---- fused LSTM epilogue (unchanged, verified).
  // C/D layout: col=lane&15, row=(lane>>4)*4+reg
  const int col0 = nBase + (lane & 15);
  const int rb = mBase + w * 64 + (lane >> 4) * 4;
#pragma unroll
  for (int nf = 0; nf < 2; ++nf) {
    const int col = col0 + nf * 16;
    const float bfv = bF[col], biv = bI[col], bov = bO[col], bgv = bG[col];
#pragma unroll
    for (int mt = 0; mt < 4; ++mt) {
#pragma unroll
      for (int r = 0; r < 4; ++r) {
        const int row = rb + mt * 16 + r;
        const size_t off = (size_t)row * OUT_DIM + col;
        float pf = acc[0][nf][mt][r] + bfv;
        float pi = acc[1][nf][mt][r] + biv;
        float po = acc[2][nf][mt][r] + bov;
        float pg = acc[3][nf][mt][r] + bgv;
        float F = 1.f / (1.f + __expf(-pf));
        float I = 1.f / (1.f + __expf(-pi));
        float O = 1.f / (1.f + __expf(-po));
        float G = tanh_fast(pg);
        float c_new = G * I + F * Cin[off];
        outC[off] = c_new;
        outY[off] = O * tanh_fast(c_new);
      }
    }
  }
}

// ---------------------------------------------------------------------------
extern "C" void kernel_launch(void* const* d_in, const int* in_sizes, int n_in,
                              void* d_out, int out_size, void* d_ws, size_t ws_size,
                              hipStream_t stream) {
  // setup_inputs order: X C H W_xf W_xg W_xi W_xo W_hf W_hg W_hi W_ho b_f b_g b_i b_o
  const float* X   = (const float*)d_in[0];
  const float* C   = (const float*)d_in[1];
  const float* H   = (const float*)d_in[2];
  const float* Wxf = (const float*)d_in[3];
  const float* Wxg = (const float*)d_in[4];
  const float* Wxi = (const float*)d_in[5];
  const float* Wxo = (const float*)d_in[6];
  const float* Whf = (const float*)d_in[7];
  const float* Whg = (const float*)d_in[8];
  const float* Whi = (const float*)d_in[9];
  const float* Who = (const float*)d_in[10];
  const float* bf_ = (const float*)d_in[11];
  const float* bg_ = (const float*)d_in[12];
  const float* bi_ = (const float*)d_in[13];
  const float* bo_ = (const float*)d_in[14];

  float* outC = (float*)d_out;
  float* outY = (float*)d_out + (size_t)BATCH * OUT_DIM;

  // workspace layout: A bf16 (32 MB) | Bt bf16 (64 MB)  => 96 MB needed
  unsigned short* A  = (unsigned short*)d_ws;
  unsigned short* Bt = A + (size_t)BATCH * KDIM;

  // 1) pack A = [X|H] -> bf16
  pack_A_kernel<<<(BATCH * KDIM / 4) / 256, 256, 0, stream>>>(X, H, A);
  // 2) pack Bt (transpose + gate concat + bf16)
  pack_B_kernel<<<64 * 256, 256, 0, stream>>>(Wxf, Wxi, Wxo, Wxg,
                                              Whf, Whi, Who, Whg, Bt);
  // 3) fused GEMM + LSTM epilogue
  dim3 grid(OUT_DIM / 32, BATCH / 256);      // (64, 16)
  lstm_gemm_fused<<<grid, 256, 0, stream>>>(A, Bt, C, bf_, bi_, bo_, bg_,
                                            outC, outY);
}

// Round 4
// 525.752 us; speedup vs baseline: 1.0419x; 1.0419x over previous
//
#include <hip/hip_runtime.h>
#include <cstdint>
#include <cstddef>

// Problem dims (fixed by reference)
#define BATCH   4096
#define IN_DIM  2048
#define OUT_DIM 2048
#define KDIM    4096   // IN_DIM + OUT_DIM
#define NT      128    // number of 32-wide K tiles

typedef __bf16 bf16x8 __attribute__((ext_vector_type(8)));
typedef float  floatx4 __attribute__((ext_vector_type(4)));

__device__ __forceinline__ unsigned short f2bf(float f) {
  unsigned int u = __float_as_uint(f);
  u += 0x7FFFu + ((u >> 16) & 1u);   // round-to-nearest-even
  return (unsigned short)(u >> 16);
}

__device__ __forceinline__ void async16(const void* g, void* l) {
  __builtin_amdgcn_global_load_lds(
      (const __attribute__((address_space(1))) unsigned int*)g,
      (__attribute__((address_space(3))) unsigned int*)l, 16, 0, 0);
}

// fast tanh via exp2-backed __expf; exact at saturation (exp overflow -> +-1)
__device__ __forceinline__ float tanh_fast(float x) {
  return 1.f - 2.f / (__expf(2.f * x) + 1.f);
}

// ---------------------------------------------------------------------------
// Pack A = [X | H] row-major 4096 x 4096 bf16   (byte-identical to verified)
// ---------------------------------------------------------------------------
__global__ __launch_bounds__(256) void pack_A_kernel(
    const float* __restrict__ X, const float* __restrict__ H,
    unsigned short* __restrict__ A) {
  int idx = blockIdx.x * 256 + threadIdx.x;   // 0 .. 4194303
  int e = idx << 2;                           // element index (groups of 4)
  int m = e >> 12;                            // /4096
  int k = e & 4095;
  const float* src = (k < IN_DIM) ? (X + (size_t)m * IN_DIM + k)
                                  : (H + (size_t)m * OUT_DIM + (k - IN_DIM));
  float4 v = *(const float4*)src;
  ushort4 o;
  o.x = f2bf(v.x); o.y = f2bf(v.y); o.z = f2bf(v.z); o.w = f2bf(v.w);
  *(ushort4*)(A + e) = o;
}

// ---------------------------------------------------------------------------
// Pack Bt: 8192(n) x 4096(k) bf16, n = gate*2048 + c, gates ordered f,i,o,g.
// (byte-identical to verified baseline)
// ---------------------------------------------------------------------------
__global__ __launch_bounds__(256) void pack_B_kernel(
    const float* __restrict__ Wxf, const float* __restrict__ Wxi,
    const float* __restrict__ Wxo, const float* __restrict__ Wxg,
    const float* __restrict__ Whf, const float* __restrict__ Whi,
    const float* __restrict__ Who, const float* __restrict__ Whg,
    unsigned short* __restrict__ Bt) {
  __shared__ float tile[64][33];
  int bx = blockIdx.x;             // 0 .. 16383
  int kT = bx & 63;                // 0..63
  int nT = bx >> 6;                // 0..255
  int k0 = kT * 64, n0 = nT * 32;
  int g = n0 >> 11;                // gate; tiles never straddle (2048%32==0)
  int c0 = n0 & 2047;
  const float* W;
  int kk0;
  if (k0 < IN_DIM) {               // 2048 % 64 == 0: no straddle in k either
    kk0 = k0;
    W = (g == 0) ? Wxf : (g == 1) ? Wxi : (g == 2) ? Wxo : Wxg;
  } else {
    kk0 = k0 - IN_DIM;
    W = (g == 0) ? Whf : (g == 1) ? Whi : (g == 2) ? Who : Whg;
  }
  int t = threadIdx.x;
#pragma unroll
  for (int i = 0; i < 2; ++i) {
    int idx = i * 256 + t;
    int lk = idx >> 3, lc = (idx & 7) * 4;
    float4 v = *(const float4*)(W + (size_t)(kk0 + lk) * 2048 + c0 + lc);
    tile[lk][lc]     = v.x;
    tile[lk][lc + 1] = v.y;
    tile[lk][lc + 2] = v.z;
    tile[lk][lc + 3] = v.w;
  }
  __syncthreads();
  int ln = t >> 3, k8 = (t & 7) * 8;
  unsigned int p[4];
#pragma unroll
  for (int j = 0; j < 4; ++j) {
    unsigned int lo = f2bf(tile[k8 + 2 * j][ln]);
    unsigned int hi = f2bf(tile[k8 + 2 * j + 1][ln]);
    p[j] = lo | (hi << 16);
  }
  uint4 o = make_uint4(p[0], p[1], p[2], p[3]);
  *(uint4*)(Bt + (size_t)(n0 + ln) * KDIM + k0 + k8) = o;
}

// ---------------------------------------------------------------------------
// Fused LSTM GEMM — counted-vmcnt deep pipeline in 64 KiB STATIC LDS.
//   512 thr (8 waves, 2M x 4N), tile 256(M) x [64 cols x 4 gates], BK=32.
//   Wave output 128(m) x [16 cols x 4 gates]; 16 MFMA per phase, 2 phases
//   per tile. LDS: 2-slot ring, slot = A[256x32] 16KB + B[256x32] 16KB.
//
//   Load groups per tile (per thread): G1 = {a1, b1, b2} (3 loads: A-rows
//   for phase A + ALL B rows), G2 = {a2} (1 load: A-rows for phase B).
//   A staged in permuted L-row order so phase-A frags are contiguous:
//     L-rows [0,128)  = phys m-rows {0-63, 128-191}  (phase A, wm 0/1)
//     L-rows [128,256)= phys m-rows {64-127, 192-255} (phase B)
//     thread t: physA = rowT + (rowT & 64), a2 = physA + 64.
//   Issue points: G2(t+1) in phase A of t (writes slot (t+1)&1 A-phaseB
//   region, whose readers = tile t-1 phase B drained before the phase-A(t)
//   barrier); G1(t+2) in phase B of t (writes slot t&1 A-phaseA + B regions,
//   whose readers = tile t phase A drained before the phase-B(t) barrier).
//   Waits (vmcnt retires in issue order; groups sized 3/1):
//     phase A(t): newer-than-G1(t) = G2(t)+G1(t+1) = 4  -> s_waitcnt vmcnt(4)
//     phase B(t): newer-than-G2(t) = G1(t+1)+G2(t+1)=4  -> s_waitcnt vmcnt(4)
//     NEVER 0 in the main loop; last tile peeled with vmcnt(1)/vmcnt(0).
//   Every wait precedes an s_barrier (asm volatile + "memory" clobber: IR
//   loads/stores and the load_lds intrinsic cannot cross it), and all
//   ds_read->MFMA lgkm waits are compiler-inserted (reads are IR-level).
//   Swizzle: linear LDS dest; stage source chunk = (t&3) ^ ((rowT>>1)&3);
//   read chunk = fk ^ ((fr>>1)&3). Fragment row bases are multiples of 16,
//   so the involutions match (baseline-verified pattern, 0 conflicts).
// ---------------------------------------------------------------------------
template <bool LAST, bool IG1, bool IG2>
__device__ __forceinline__ void do_tile(
    const char* sl, char* sn,
    const char* aG_1, const char* aG_2, const char* bG_1, const char* bG_2,
    unsigned kbG1, unsigned kbG2, int t16,
    int aOffA, int bOff, floatx4 (&acc)[4][8]) {
  bf16x8 af[4], bfr[4];
  // ================= phase A =================
  if (LAST) asm volatile("s_waitcnt vmcnt(1)" ::: "memory");
  else      asm volatile("s_waitcnt vmcnt(4)" ::: "memory");
  asm volatile("s_barrier" ::: "memory");
#pragma unroll
  for (int mt = 0; mt < 4; ++mt)
    af[mt] = *(const bf16x8*)(sl + aOffA + mt * 1024);
#pragma unroll
  for (int nf = 0; nf < 4; ++nf)
    bfr[nf] = *(const bf16x8*)(sl + bOff + nf * 4096);
  if (IG2) async16(aG_2 + kbG2, sn + 8192 + t16);
  __builtin_amdgcn_s_setprio(1);
#pragma unroll
  for (int nf = 0; nf < 4; ++nf)
#pragma unroll
    for (int mt = 0; mt < 4; ++mt)
      acc[nf][mt] = __builtin_amdgcn_mfma_f32_16x16x32_bf16(
          af[mt], bfr[nf], acc[nf][mt], 0, 0, 0);
  __builtin_amdgcn_s_setprio(0);
  // ================= phase B =================
  if (LAST) asm volatile("s_waitcnt vmcnt(0)" ::: "memory");
  else      asm volatile("s_waitcnt vmcnt(4)" ::: "memory");
  asm volatile("s_barrier" ::: "memory");
#pragma unroll
  for (int mt = 0; mt < 4; ++mt)
    af[mt] = *(const bf16x8*)(sl + aOffA + 8192 + mt * 1024);
  if (IG1) {
    char* sc = const_cast<char*>(sl);     // G1(t+2) targets the CURRENT slot
    async16(aG_1 + kbG1, sc + t16);
    async16(bG_1 + kbG1, sc + 16384 + t16);
    async16(bG_2 + kbG1, sc + 24576 + t16);
  }
  __builtin_amdgcn_s_setprio(1);
#pragma unroll
  for (int nf = 0; nf < 4; ++nf)
#pragma unroll
    for (int mt = 0; mt < 4; ++mt)
      acc[nf][mt + 4] = __builtin_amdgcn_mfma_f32_16x16x32_bf16(
          af[mt], bfr[nf], acc[nf][mt + 4], 0, 0, 0);
  __builtin_amdgcn_s_setprio(0);
}

__global__ __launch_bounds__(512, 2) void lstm_gemm_fused(
    const unsigned short* __restrict__ A,    // 4096 x 4096 bf16
    const unsigned short* __restrict__ Bt,   // 8192 x 4096 bf16
    const float* __restrict__ Cin,           // 4096 x 2048
    const float* __restrict__ bF, const float* __restrict__ bI,
    const float* __restrict__ bO, const float* __restrict__ bG,
    float* __restrict__ outC, float* __restrict__ outY) {
  __shared__ __align__(16) char smem[65536];   // 2 slots x 32 KB, static

  const int t = threadIdx.x;                 // 0..511
  const int lane = t & 63;
  const int w = t >> 6;                      // wave 0..7
  const int wm = w >> 2;                     // m-half 0..1 (128 rows each)
  const int wn = w & 3;                      // n-quarter (16 cols x 4 gates)

  // bijective XCD swizzle (512 % 8 == 0): XCD x gets 64 contiguous wgids
  // = 2 full by-rows -> per-XCD A panels L2-resident.
  const int orig = blockIdx.x;
  const int wgid = (orig & 7) * 64 + (orig >> 3);
  const int bx = wgid & 31;                  // n tile: 64 cols per gate
  const int by = wgid >> 5;                  // m tile: 256 rows
  const int mBase = by * 256;

  floatx4 acc[4][8];                         // [gate][m-frag]
#pragma unroll
  for (int g = 0; g < 4; ++g)
#pragma unroll
    for (int mt = 0; mt < 8; ++mt) acc[g][mt] = (floatx4){0.f, 0.f, 0.f, 0.f};

  // ---- staging: thread t owns LDS L-row rowT = t>>2, chunk t&3 (linear
  // dest t*16 per 8 KB region); global source chunk pre-swizzled.
  const int rowT = t >> 2;                   // 0..127
  const int cswz = ((t & 3) ^ ((t >> 3) & 3)) * 16;     // byte offset in row
  const int physA = rowT + (rowT & 64);      // {0-63,128-191}
  const char* aG_1 = (const char*)A + ((size_t)(mBase + physA) * KDIM) * 2 + cswz;
  const char* aG_2 = aG_1 + (size_t)64 * KDIM * 2;      // {64-127,192-255}
  // B rows: L-rows [0,128) = gates 0,1 (64 rows each); [128,256) = gates 2,3
  const int bRow = (rowT >> 6) * 2048 + bx * 64 + (rowT & 63);
  const char* bG_1 = (const char*)Bt + ((size_t)bRow * KDIM) * 2 + cswz;
  const char* bG_2 = bG_1 + (size_t)4096 * KDIM * 2;    // gates 2,3
  const int t16 = t * 16;

  // ---- fragment read offsets (L-row*64B + swizzled chunk*16B)
  const int fr = lane & 15;
  const int fkxB = (((lane >> 4) ^ ((fr >> 1) & 3))) * 16;
  // phase A: L-row = wm*64 + mt*16 + fr (phys m = wm*128 + mt*16 + fr)
  const int aOffA = (wm * 64 + fr) * 64 + fkxB;         // + mt*1024; +8192 ph.B
  // B: L-row = nf*64 + wn*16 + fr  (nf == gate)
  const int bOff = 16384 + (wn * 16 + fr) * 64 + fkxB;  // + nf*4096

  // ---- prologue: issue G1(0), G2(0), G1(1)  (7 loads, in this order)
  async16(aG_1,      smem + t16);
  async16(bG_1,      smem + 16384 + t16);
  async16(bG_2,      smem + 24576 + t16);
  async16(aG_2,      smem + 8192 + t16);
  async16(aG_1 + 64, smem + 32768 + t16);
  async16(bG_1 + 64, smem + 32768 + 16384 + t16);
  async16(bG_2 + 64, smem + 32768 + 24576 + t16);

  // ---- main loop: tiles 0 .. NT-3 steady; peel NT-2 (no G1) and NT-1
  for (int tt = 0; tt < NT - 2; ++tt) {
    const char* sl = smem + (tt & 1) * 32768;
    char* sn = smem + ((tt + 1) & 1) * 32768;
    do_tile<false, true, true>(sl, sn, aG_1, aG_2, bG_1, bG_2,
                               (unsigned)(tt + 2) * 64, (unsigned)(tt + 1) * 64,
                               t16, aOffA, bOff, acc);
  }
  {
    const int tt = NT - 2;
    const char* sl = smem + (tt & 1) * 32768;
    char* sn = smem + ((tt + 1) & 1) * 32768;
    do_tile<false, false, true>(sl, sn, aG_1, aG_2, bG_1, bG_2,
                                0, (unsigned)(tt + 1) * 64,
                                t16, aOffA, bOff, acc);
  }
  {
    const int tt = NT - 1;
    const char* sl = smem + (tt & 1) * 32768;
    char* sn = smem + ((tt + 1) & 1) * 32768;
    do_tile<true, false, false>(sl, sn, aG_1, aG_2, bG_1, bG_2,
                                0, 0, t16, aOffA, bOff, acc);
  }

  // ---- fused LSTM epilogue. C/D: col=lane&15, row=(lane>>4)*4+reg.
  // acc[nf] is gate nf (B L-row blocks of 64 = gates) at a fixed col/lane.
  const int col = bx * 64 + wn * 16 + fr;    // 0..2047
  const float bfv = bF[col], biv = bI[col], bov = bO[col], bgv = bG[col];
  const int rb = mBase + wm * 128 + ((lane >> 4) << 2);
#pragma unroll
  for (int mt = 0; mt < 8; ++mt) {
#pragma unroll
    for (int r = 0; r < 4; ++r) {
      const int row = rb + mt * 16 + r;
      const size_t off = (size_t)row * OUT_DIM + col;
      float pf = acc[0][mt][r] + bfv;
      float pi = acc[1][mt][r] + biv;
      float po = acc[2][mt][r] + bov;
      float pg = acc[3][mt][r] + bgv;
      float F = 1.f / (1.f + __expf(-pf));
      float I = 1.f / (1.f + __expf(-pi));
      float O = 1.f / (1.f + __expf(-po));
      float G = tanh_fast(pg);
      float c_new = G * I + F * Cin[off];
      outC[off] = c_new;
      outY[off] = O * tanh_fast(c_new);
    }
  }
}

// ---------------------------------------------------------------------------
extern "C" void kernel_launch(void* const* d_in, const int* in_sizes, int n_in,
                              void* d_out, int out_size, void* d_ws, size_t ws_size,
                              hipStream_t stream) {
  // setup_inputs order: X C H W_xf W_xg W_xi W_xo W_hf W_hg W_hi W_ho b_f b_g b_i b_o
  const float* X   = (const float*)d_in[0];
  const float* C   = (const float*)d_in[1];
  const float* H   = (const float*)d_in[2];
  const float* Wxf = (const float*)d_in[3];
  const float* Wxg = (const float*)d_in[4];
  const float* Wxi = (const float*)d_in[5];
  const float* Wxo = (const float*)d_in[6];
  const float* Whf = (const float*)d_in[7];
  const float* Whg = (const float*)d_in[8];
  const float* Whi = (const float*)d_in[9];
  const float* Who = (const float*)d_in[10];
  const float* bf_ = (const float*)d_in[11];
  const float* bg_ = (const float*)d_in[12];
  const float* bi_ = (const float*)d_in[13];
  const float* bo_ = (const float*)d_in[14];

  float* outC = (float*)d_out;
  float* outY = (float*)d_out + (size_t)BATCH * OUT_DIM;

  // workspace layout: A bf16 (32 MB) | Bt bf16 (64 MB)  => 96 MB needed
  unsigned short* A  = (unsigned short*)d_ws;
  unsigned short* Bt = A + (size_t)BATCH * KDIM;

  // 1) pack A = [X|H] -> bf16
  pack_A_kernel<<<(BATCH * KDIM / 4) / 256, 256, 0, stream>>>(X, H, A);
  // 2) pack Bt (transpose + gate concat + bf16)
  pack_B_kernel<<<64 * 256, 256, 0, stream>>>(Wxf, Wxi, Wxo, Wxg,
                                              Whf, Whi, Who, Whg, Bt);
  // 3) fused GEMM + LSTM epilogue: 512 blocks (32 bx x 16 by) x 512 thr
  lstm_gemm_fused<<<dim3(512), dim3(512), 0, stream>>>(
      A, Bt, C, bf_, bi_, bo_, bg_, outC, outY);
}